// Round 3
// baseline (470.667 us; speedup 1.0000x reference)
//
#include <hip/hip_runtime.h>

// HealEncoding v5: persistent blocks + 2-deep REGISTER double-buffered tile loop.
//
// v4 post-mortem: latency-bound (VALUBusy 23%, HBM 20%, no pipe saturated).
// VGPR=40 showed the compiler kept ONE tile in flight: issue 18 loads -> wait
// ~600-900cy -> ~300cy compute. v5 pipelines two tiles in named register sets
// (A/B, unroll-by-2 -> all array indices compile-time, rule #20), so each
// tile's loads have a full compute phase + the other set's load-issue in
// flight before consumption. Compiler emits counted vmcnt(N) for this shape.
// Grid = 1024 = 256 CU x 4 blocks (VGPR ~80 -> 16 waves/CU cap) so every
// block is resident: persistent, no queued-block tail.
//
// params        [4, 792, 2]  f32   (25 KB -> LDS, loaded once per block)
// pixel_latlon  [4, B, 2]    f32
// neigh_latlon  [4, 8B, 2]   f32   (element i = j*B + b)
// pixel_index   [4, B]       i32
// neigh_index   [4, 8, B]    i32   (-1 = missing -> contributes 0)
// out           [B, 8]       f32   out[b, 4*f + l] = res[l][b][f]

#define NLEV 4
#define MAXSZ 792
#define TABSZ (NLEV * MAXSZ * 2)   // 6336 floats = 25344 B
#define PPB 64                     // pixels per tile (block = 256 = 64 px x 4 lvl)

// issue all 18 global loads for one tile into a named register set
#define ISSUE_LOADS(pi_, pll_, ni_, nl_, tt)                  \
    {                                                         \
        const int b_ = min((tt) * PPB + bl, B - 1);           \
        pi_  = pixel_index[pb + b_];                          \
        pll_ = pll2[pb + b_];                                 \
        _Pragma("unroll")                                     \
        for (int j = 0; j < 8; ++j) {                         \
            ni_[j] = neigh_index[nb + j * B + b_];            \
            nl_[j] = nll2[nb + j * B + b_];                   \
        }                                                     \
    }

// consume one register set: weights, LDS gathers, residual, in-wave pairing,
// coalesced float2 store straight from registers
#define COMPUTE_STORE(pi_, pll_, ni_, nl_, tt)                \
    {                                                         \
        float a0 = 0.0f, a1 = 0.0f;                           \
        _Pragma("unroll")                                     \
        for (int j = 0; j < 8; ++j) {                         \
            float dth = nl_[j].x - pll_.x;                    \
            float dph = nl_[j].y - pll_.y;                    \
            float d   = sqrtf(dth * dth + dph * dph);         \
            float w   = (ni_[j] >= 0) ? (1.0f / d) : 0.0f;    \
            float2 r  = sp2[lb + (ni_[j] >= 0 ? ni_[j] : 0)]; \
            a0 += w * r.x;                                    \
            a1 += w * r.y;                                    \
        }                                                     \
        float2 m = sp2[lb + (pi_ < 0 ? 768 : pi_)];           \
        a0 += m.x;                                            \
        a1 += m.y;                                            \
        const bool odd = (l & 1);                             \
        float x = __shfl_xor(odd ? a0 : a1, 1);               \
        float2 st = odd ? make_float2(x, a1)                  \
                        : make_float2(a0, x);                 \
        const int col = odd ? (l + 3) : l;                    \
        const int bo = (tt) * PPB + bl;                       \
        if (bo < B)                                           \
            *(float2*)(out + (size_t)bo * 8 + col) = st;      \
    }

__global__ __launch_bounds__(256, 4) void heal_encoding_kernel(
    const float* __restrict__ params,
    const float* __restrict__ pixel_latlon,
    const float* __restrict__ neigh_latlon,
    const int*   __restrict__ pixel_index,
    const int*   __restrict__ neigh_index,
    float* __restrict__ out,
    int B, int ntiles)
{
    __shared__ float stab[TABSZ];   // 25344 B

    const int tid = threadIdx.x;
    const int bl  = tid >> 2;      // pixel within tile
    const int l   = tid & 3;       // level 0..3

    // ---- stage table once per persistent block ----
    {
        const float4* p4  = (const float4*)params;
        float4*       st4 = (float4*)stab;
        for (int i = tid; i < TABSZ / 4; i += 256)
            st4[i] = p4[i];
    }
    __syncthreads();               // the only barrier this block executes

    const float2* sp2  = (const float2*)stab;
    const float2* pll2 = (const float2*)pixel_latlon;
    const float2* nll2 = (const float2*)neigh_latlon;
    const int lb = l * MAXSZ;      // table base for this level (float2 units)
    const int pb = l * B;          // base into pixel arrays
    const int nb = l * 8 * B;      // base into neigh arrays (<= 24e6, int ok)

    const int g    = gridDim.x;
    const int tmax = ntiles - 1;
    const int iters = (ntiles - blockIdx.x + g - 1) / g;   // tiles this block owns

    // two named register sets (compile-time indices only -> stays in VGPRs)
    int piA; float2 pllA; int niA[8]; float2 nlA[8];
    int piB; float2 pllB; int niB[8]; float2 nlB[8];

    int t = blockIdx.x;
    ISSUE_LOADS(piA, pllA, niA, nlA, t);                 // prologue: tile 0 in flight

    for (int i = 0; i < iters; i += 2) {
        const int t1 = min(t + g, tmax);
        ISSUE_LOADS(piB, pllB, niB, nlB, t1);            // prefetch next into B
        COMPUTE_STORE(piA, pllA, niA, nlA, t);           // consume A (waits A only)

        const int t2 = min(t1 + g, tmax);
        ISSUE_LOADS(piA, pllA, niA, nlA, t2);            // prefetch next+1 into A
        if (i + 1 < iters)
            COMPUTE_STORE(piB, pllB, niB, nlB, t + g);   // consume B

        t += 2 * g;
    }
}

extern "C" void kernel_launch(void* const* d_in, const int* in_sizes, int n_in,
                              void* d_out, int out_size, void* d_ws, size_t ws_size,
                              hipStream_t stream) {
    const float* params       = (const float*)d_in[0];
    const float* pixel_latlon = (const float*)d_in[1];
    const float* neigh_latlon = (const float*)d_in[2];
    const int*   pixel_index  = (const int*)d_in[3];
    const int*   neigh_index  = (const int*)d_in[4];
    float* out = (float*)d_out;

    int B = in_sizes[3] / NLEV;              // pixel_index has 4*B elements
    int ntiles = (B + PPB - 1) / PPB;        // B=1e6 -> 15625 tiles
    int blocks = 1024;                       // 256 CU x 4 blocks/CU (VGPR-capped
    if (blocks > ntiles) blocks = ntiles;    //  residency) -> fully persistent
    heal_encoding_kernel<<<blocks, 256, 0, stream>>>(
        params, pixel_latlon, neigh_latlon, pixel_index, neigh_index, out, B, ntiles);
}